// Round 3
// baseline (567.778 us; speedup 1.0000x reference)
//
#include <hip/hip_runtime.h>
#include <hip/hip_bf16.h>
#include <cstdint>
#include <cstddef>

#define S_TOK 2048
#define M_DIM 768
#define H_DIM 3072
#define E_NUM 16
#define CAP   256   // 2*S/E

using s16x8 = __attribute__((ext_vector_type(8))) short;  // 8 bf16 (4 VGPRs)
using f32x4 = __attribute__((ext_vector_type(4))) float;

__device__ __forceinline__ unsigned short f2bf(float f) {
    unsigned u = __float_as_uint(f);
    unsigned r = 0x7fffu + ((u >> 16) & 1u);
    return (unsigned short)((u + r) >> 16);
}

__device__ __forceinline__ void async16(const void* g, void* l) {
    __builtin_amdgcn_global_load_lds((const __attribute__((address_space(1))) void*)g,
                                     (__attribute__((address_space(3))) void*)l, 16, 0, 0);
}

// ---------------------------------------------------------------------------
// Kernel 1: gating — logits = x@wg, softmax, top1/top2 (one wave per token).
// Also emits xb = bf16(x) (+ zero row at ntok) as a side product.
// ---------------------------------------------------------------------------
__global__ void gating_kernel(const float* __restrict__ x, const float* __restrict__ wg,
                              int* __restrict__ e1o, int* __restrict__ e2o,
                              float* __restrict__ g1o, float* __restrict__ g2o,
                              unsigned short* __restrict__ xb, int ntok) {
    if (blockIdx.x == 0) {  // zero row for dropped-token gather
        for (int m = threadIdx.x; m < M_DIM; m += blockDim.x)
            xb[(size_t)ntok * M_DIM + m] = 0;
    }
    int gid  = blockIdx.x * blockDim.x + threadIdx.x;
    int tok  = gid >> 6;
    int lane = threadIdx.x & 63;
    if (tok >= ntok) return;
    const float* xr = x + (size_t)tok * M_DIM;
    unsigned short* xbr = xb + (size_t)tok * M_DIM;
    float acc[E_NUM];
#pragma unroll
    for (int e = 0; e < E_NUM; ++e) acc[e] = 0.f;
    for (int m = lane; m < M_DIM; m += 64) {
        float xv = xr[m];
        xbr[m] = f2bf(xv);
        const float* wr = wg + (size_t)m * E_NUM;
#pragma unroll
        for (int e = 0; e < E_NUM; ++e) acc[e] += xv * wr[e];
    }
#pragma unroll
    for (int off = 32; off >= 1; off >>= 1) {
#pragma unroll
        for (int e = 0; e < E_NUM; ++e) acc[e] += __shfl_xor(acc[e], off, 64);
    }
    if (lane == 0) {
        float mx = acc[0];
#pragma unroll
        for (int e = 1; e < E_NUM; ++e) mx = fmaxf(mx, acc[e]);
        float p[E_NUM]; float s = 0.f;
#pragma unroll
        for (int e = 0; e < E_NUM; ++e) { p[e] = expf(acc[e] - mx); s += p[e]; }
        float inv = 1.f / s;
        int b1 = 0; float v1 = -1.f;
#pragma unroll
        for (int e = 0; e < E_NUM; ++e) { if (p[e] > v1) { v1 = p[e]; b1 = e; } }
        int b2 = 0; float v2 = -1.f;
#pragma unroll
        for (int e = 0; e < E_NUM; ++e) { if (e != b1 && p[e] > v2) { v2 = p[e]; b2 = e; } }
        e1o[tok] = b1; e2o[tok] = b2;
        g1o[tok] = v1 * inv; g2o[tok] = v2 * inv;
    }
}

// ---------------------------------------------------------------------------
// Kernel 2: assignment — capacity positions via ballot prefix scan.
// Emits tfs (slot -> token) and wslot (slot -> combine weight).
// ---------------------------------------------------------------------------
__global__ void assign_kernel(const int* __restrict__ e1a, const int* __restrict__ e2a,
                              const float* __restrict__ g1a, const float* __restrict__ g2a,
                              int* __restrict__ slot1, int* __restrict__ slot2,
                              float* __restrict__ wslot,
                              int* __restrict__ tfs, int G) {
    int g    = blockIdx.x;
    int tid  = threadIdx.x;
    int w    = tid >> 6;
    int lane = tid & 63;
    __shared__ int cnt1s[E_NUM];

    for (int i = tid; i < E_NUM * CAP; i += 1024) tfs[(size_t)g * E_NUM * CAP + i] = -1;
    __syncthreads();

    {
        int vals[S_TOK / 64];
#pragma unroll
        for (int it = 0; it < S_TOK / 64; ++it) vals[it] = e1a[g * S_TOK + it * 64 + lane];
        int cnt = 0;
#pragma unroll
        for (int it = 0; it < S_TOK / 64; ++it) {
            int base = it * 64;
            int t = g * S_TOK + base + lane;
            bool pred = (vals[it] == w);
            unsigned long long bal = __ballot(pred);
            int prefix = __popcll(bal & ((1ull << lane) - 1ull));
            if (pred) {
                int pos = cnt + prefix;
                if (pos < CAP) {
                    slot1[t] = w * CAP + pos;
                    tfs[((size_t)g * E_NUM + w) * CAP + pos] = base + lane;
                } else {
                    slot1[t] = -1;
                }
            }
            cnt += __popcll(bal);
        }
        if (lane == 0) cnt1s[w] = cnt < CAP ? cnt : CAP;
    }
    __syncthreads();
    {
        int vals[S_TOK / 64];
#pragma unroll
        for (int it = 0; it < S_TOK / 64; ++it) vals[it] = e2a[g * S_TOK + it * 64 + lane];
        int cnt = cnt1s[w];
#pragma unroll
        for (int it = 0; it < S_TOK / 64; ++it) {
            int base = it * 64;
            int t = g * S_TOK + base + lane;
            bool pred = (vals[it] == w);
            unsigned long long bal = __ballot(pred);
            int prefix = __popcll(bal & ((1ull << lane) - 1ull));
            if (pred) {
                int pos = cnt + prefix;
                if (pos < CAP) {
                    slot2[t] = w * CAP + pos;
                    tfs[((size_t)g * E_NUM + w) * CAP + pos] = base + lane;
                } else {
                    slot2[t] = -1;
                }
            }
            cnt += __popcll(bal);
        }
    }
    __syncthreads();
    // per-slot combine weights
    for (int t = tid; t < S_TOK; t += 1024) {
        int gt = g * S_TOK + t;
        int s1 = slot1[gt], s2 = slot2[gt];
        float a = s1 >= 0 ? g1a[gt] : 0.f;
        float b = s2 >= 0 ? g2a[gt] : 0.f;
        float denom = a + b;
        if (!(denom > 0.f)) denom = 1.f;
        if (s1 >= 0) wslot[(size_t)g * E_NUM * CAP + s1] = a / denom;
        if (s2 >= 0) wslot[(size_t)g * E_NUM * CAP + s2] = b / denom;
    }
}

// ---------------------------------------------------------------------------
// Kernel 3: transpose+convert: src [E][R][C] fp32 -> dst [E][C][R] bf16
// ---------------------------------------------------------------------------
__global__ __launch_bounds__(256) void transpose_conv_kernel(const float* __restrict__ src,
                                                             unsigned short* __restrict__ dst,
                                                             int R, int C) {
    __shared__ float T[64][65];
    int e  = blockIdx.z;
    int c0 = blockIdx.x * 64;
    int r0 = blockIdx.y * 64;
    int tid = threadIdx.x;
    int lx = tid & 63, ly = tid >> 6;
    const float* S = src + (size_t)e * R * C;
#pragma unroll
    for (int i = 0; i < 16; ++i) {
        int r = i * 4 + ly;
        T[r][lx] = S[(size_t)(r0 + r) * C + c0 + lx];
    }
    __syncthreads();
    unsigned short* D = dst + (size_t)e * C * R;
#pragma unroll
    for (int i = 0; i < 16; ++i) {
        int c = i * 4 + ly;
        D[(size_t)(c0 + c) * R + r0 + lx] = f2bf(T[lx][c]);
    }
}

// ---------------------------------------------------------------------------
// Kernel 4: gemm1 — h[z][CAP][H] = relu(gather(xb) @ wiT^T), K = 768.
// Tile 256x128 (full CAP), 512 threads / 8 waves, BK=32, async LDS staging.
// grid: x = n_tile*2 + g (48), z = e (16)
// ---------------------------------------------------------------------------
__global__ __launch_bounds__(512) void gemm1_kernel(
        const unsigned short* __restrict__ A,    // xb [ntok+1][M]
        const unsigned short* __restrict__ B,    // wiT [E][H][M]
        const int* __restrict__ tfs,
        unsigned short* __restrict__ Hout, int G) {
    __shared__ unsigned short As[256 * 32];
    __shared__ unsigned short Bs[128 * 32];
    __shared__ int rowtok[256];

    int e  = blockIdx.z;
    int n0 = (blockIdx.x >> 1) * 128;
    int g  = blockIdx.x & 1;
    int z  = e * G + g;
    int tid = threadIdx.x;

    if (tid < 256) rowtok[tid] = tfs[((size_t)g * E_NUM + e) * CAP + tid];
    __syncthreads();

    int r4 = tid >> 2, l4 = tid & 3;     // r4 in [0,128)
    int t0 = rowtok[r4], t1 = rowtok[128 + r4];
    size_t row0 = (t0 < 0) ? (size_t)(G * S_TOK) : (size_t)(g * S_TOK + t0);
    size_t row1 = (t1 < 0) ? (size_t)(G * S_TOK) : (size_t)(g * S_TOK + t1);
    const unsigned short* apt0 = A + row0 * M_DIM + l4 * 8;
    const unsigned short* apt1 = A + row1 * M_DIM + l4 * 8;
    const unsigned short* bpt  = B + (size_t)e * H_DIM * M_DIM + ((size_t)n0 + r4) * M_DIM + l4 * 8;

    int wv = tid >> 6;                   // wave 0..7
    unsigned short* as0 = &As[(wv * 16) * 32];
    unsigned short* as1 = &As[(128 + wv * 16) * 32];
    unsigned short* bs  = &Bs[(wv * 16) * 32];

    int lane = tid & 63;
    int r = lane & 15, q = lane >> 4;
    int wm = wv & 3, wn = wv >> 2;       // m-quadrant (0..3), n-half (0..1)

    f32x4 acc[4][4];
#pragma unroll
    for (int i = 0; i < 4; ++i)
#pragma unroll
        for (int j = 0; j < 4; ++j) acc[i][j] = (f32x4)(0.f);

    for (int k0 = 0; k0 < M_DIM; k0 += 32) {
        async16(apt0, as0);
        async16(apt1, as1);
        async16(bpt, bs);
        apt0 += 32; apt1 += 32; bpt += 32;
        __syncthreads();
        s16x8 af[4], bfr[4];
#pragma unroll
        for (int i = 0; i < 4; ++i)
            af[i] = *(const s16x8*)&As[(wm * 64 + i * 16 + r) * 32 + q * 8];
#pragma unroll
        for (int j = 0; j < 4; ++j)
            bfr[j] = *(const s16x8*)&Bs[(wn * 64 + j * 16 + r) * 32 + q * 8];
#pragma unroll
        for (int i = 0; i < 4; ++i)
#pragma unroll
            for (int j = 0; j < 4; ++j)
                acc[i][j] = __builtin_amdgcn_mfma_f32_16x16x32_bf16(af[i], bfr[j], acc[i][j], 0, 0, 0);
        __syncthreads();
    }

#pragma unroll
    for (int i = 0; i < 4; ++i) {
#pragma unroll
        for (int v = 0; v < 4; ++v) {
            int m_loc = wm * 64 + i * 16 + q * 4 + v;
            unsigned short* row = Hout + ((size_t)z * CAP + m_loc) * H_DIM + n0;
#pragma unroll
            for (int j = 0; j < 4; ++j) {
                int n_loc = wn * 64 + j * 16 + r;
                row[n_loc] = f2bf(fmaxf(acc[i][j][v], 0.f));
            }
        }
    }
}

// ---------------------------------------------------------------------------
// Kernel 5: zero the output buffer (it is poisoned before every launch)
// ---------------------------------------------------------------------------
__global__ void zero_kernel(float4* __restrict__ p, int n4) {
    int i = blockIdx.x * blockDim.x + threadIdx.x;
    if (i < n4) p[i] = make_float4(0.f, 0.f, 0.f, 0.f);
}

// ---------------------------------------------------------------------------
// Kernel 6: gemm2 — split-K x2, 128x128 tile, fused weighted atomic combine:
// out[token][n] += wslot[slot] * (h[slot] @ woT^T)[n]
// grid: x = n_tile (6), y = c_tile*2 + g (4), z = kc*16 + e (32)
// ---------------------------------------------------------------------------
__global__ __launch_bounds__(256) void gemm2_kernel(
        const unsigned short* __restrict__ A,   // h [32][CAP][H]
        const unsigned short* __restrict__ B,   // woT [E][M][H]
        const int* __restrict__ tfs,
        const float* __restrict__ wslot,
        float* __restrict__ out, int G) {
    __shared__ unsigned short As[128 * 32];
    __shared__ unsigned short Bs[128 * 32];
    __shared__ int   rowtok[128];
    __shared__ float rowwt[128];

    int e  = blockIdx.z & 15;
    int kc = blockIdx.z >> 4;           // 0,1
    int n0 = blockIdx.x * 128;
    int c0 = (blockIdx.y >> 1) * 128;
    int g  = blockIdx.y & 1;
    int z  = e * G + g;
    int tid = threadIdx.x;

    if (tid < 128) {
        size_t sidx = ((size_t)g * E_NUM + e) * CAP + c0 + tid;
        rowtok[tid] = tfs[sidx];
        rowwt[tid]  = wslot[sidx];
    }

    const int KC = H_DIM / 2;           // 1536
    int kb = kc * KC;
    int r4 = tid >> 2, l4 = tid & 3;    // r4 in [0,64)
    const unsigned short* apt0 = A + ((size_t)z * CAP + c0 + r4) * H_DIM + kb + l4 * 8;
    const unsigned short* apt1 = apt0 + (size_t)64 * H_DIM;
    const unsigned short* bpt0 = B + (size_t)e * M_DIM * H_DIM + ((size_t)n0 + r4) * H_DIM + kb + l4 * 8;
    const unsigned short* bpt1 = bpt0 + (size_t)64 * H_DIM;

    int wv = tid >> 6;
    unsigned short* as0 = &As[(wv * 16) * 32];
    unsigned short* as1 = &As[(64 + wv * 16) * 32];
    unsigned short* bs0 = &Bs[(wv * 16) * 32];
    unsigned short* bs1 = &Bs[(64 + wv * 16) * 32];

    int lane = tid & 63;
    int r = lane & 15, q = lane >> 4;
    int wm = wv & 1, wn = wv >> 1;

    f32x4 acc[4][4];
#pragma unroll
    for (int i = 0; i < 4; ++i)
#pragma unroll
        for (int j = 0; j < 4; ++j) acc[i][j] = (f32x4)(0.f);

    for (int k0 = 0; k0 < KC; k0 += 32) {
        async16(apt0, as0);
        async16(apt1, as1);
        async16(bpt0, bs0);
        async16(bpt1, bs1);
        apt0 += 32; apt1 += 32; bpt0 += 32; bpt1 += 32;
        __syncthreads();
        s16x8 af[4], bfr[4];
#pragma unroll
        for (int i = 0; i < 4; ++i)
            af[i] = *(const s16x8*)&As[(wm * 64 + i * 16 + r) * 32 + q * 8];
#pragma unroll
        for (int j = 0; j < 4; ++j)
            bfr[j] = *(const s16x8*)&Bs[(wn * 64 + j * 16 + r) * 32 + q * 8];
#pragma unroll
        for (int i = 0; i < 4; ++i)
#pragma unroll
            for (int j = 0; j < 4; ++j)
                acc[i][j] = __builtin_amdgcn_mfma_f32_16x16x32_bf16(af[i], bfr[j], acc[i][j], 0, 0, 0);
        __syncthreads();
    }

    // fused weighted combine: atomicAdd into out[token]
#pragma unroll
    for (int i = 0; i < 4; ++i) {
#pragma unroll
        for (int v = 0; v < 4; ++v) {
            int m_loc = wm * 64 + i * 16 + q * 4 + v;
            int tok = rowtok[m_loc];
            if (tok < 0) continue;
            float w = rowwt[m_loc];
            float* orow = out + ((size_t)(g * S_TOK + tok)) * M_DIM + n0;
#pragma unroll
            for (int j = 0; j < 4; ++j) {
                int n_loc = wn * 64 + j * 16 + r;
                atomicAdd(&orow[n_loc], w * acc[i][j][v]);
            }
        }
    }
}

// ---------------------------------------------------------------------------
extern "C" void kernel_launch(void* const* d_in, const int* in_sizes, int n_in,
                              void* d_out, int out_size, void* d_ws, size_t ws_size,
                              hipStream_t stream) {
    const float* x  = (const float*)d_in[0];
    const float* wg = (const float*)d_in[1];
    const float* wi = (const float*)d_in[2];
    const float* wo = (const float*)d_in[3];
    float* out = (float*)d_out;

    int ntok = in_sizes[0] / M_DIM;   // 4096
    int G = ntok / S_TOK;             // 2

    char* wsp = (char*)d_ws;
    auto carve = [&](size_t bytes) {
        void* p = (void*)wsp;
        wsp += (bytes + 255) & ~(size_t)255;
        return p;
    };
    int*   e1    = (int*)carve((size_t)ntok * 4);
    int*   e2    = (int*)carve((size_t)ntok * 4);
    float* g1    = (float*)carve((size_t)ntok * 4);
    float* g2    = (float*)carve((size_t)ntok * 4);
    int*   slot1 = (int*)carve((size_t)ntok * 4);
    int*   slot2 = (int*)carve((size_t)ntok * 4);
    float* wslot = (float*)carve((size_t)G * E_NUM * CAP * 4);
    int*   tfs   = (int*)carve((size_t)G * E_NUM * CAP * 4);
    unsigned short* xb  = (unsigned short*)carve((size_t)(ntok + 1) * M_DIM * 2);
    unsigned short* wiT = (unsigned short*)carve((size_t)E_NUM * H_DIM * M_DIM * 2);
    unsigned short* woT = (unsigned short*)carve((size_t)E_NUM * M_DIM * H_DIM * 2);
    unsigned short* h   = (unsigned short*)carve((size_t)E_NUM * G * CAP * H_DIM * 2);

    gating_kernel<<<(ntok * 64 + 255) / 256, 256, 0, stream>>>(x, wg, e1, e2, g1, g2, xb, ntok);
    assign_kernel<<<G, 1024, 0, stream>>>(e1, e2, g1, g2, slot1, slot2, wslot, tfs, G);

    // wi [E][M][H] -> wiT [E][H][M]
    transpose_conv_kernel<<<dim3(H_DIM / 64, M_DIM / 64, E_NUM), 256, 0, stream>>>(wi, wiT, M_DIM, H_DIM);
    // wo [E][H][M] -> woT [E][M][H]
    transpose_conv_kernel<<<dim3(M_DIM / 64, H_DIM / 64, E_NUM), 256, 0, stream>>>(wo, woT, H_DIM, M_DIM);

    gemm1_kernel<<<dim3((H_DIM / 128) * 2, 1, E_NUM), 512, 0, stream>>>(xb, wiT, tfs, h, G);

    int n4 = ntok * M_DIM / 4;
    zero_kernel<<<(n4 + 255) / 256, 256, 0, stream>>>((float4*)out, n4);

    gemm2_kernel<<<dim3(M_DIM / 128, 2 * 2, 2 * E_NUM), 256, 0, stream>>>(h, woT, tfs, wslot, out, G);
}

// Round 4
// 552.958 us; speedup vs baseline: 1.0268x; 1.0268x over previous
//
#include <hip/hip_runtime.h>
#include <hip/hip_bf16.h>
#include <cstdint>
#include <cstddef>

#define S_TOK 2048
#define M_DIM 768
#define H_DIM 3072
#define E_NUM 16
#define CAP   256   // 2*S/E

using s16x8 = __attribute__((ext_vector_type(8))) short;  // 8 bf16 (4 VGPRs)
using f32x4 = __attribute__((ext_vector_type(4))) float;

__device__ __forceinline__ unsigned short f2bf(float f) {
    unsigned u = __float_as_uint(f);
    unsigned r = 0x7fffu + ((u >> 16) & 1u);
    return (unsigned short)((u + r) >> 16);
}

// LDS dest is wave-uniform base; HW appends lane*16.
__device__ __forceinline__ void async16(const void* g, void* l) {
    __builtin_amdgcn_global_load_lds((const __attribute__((address_space(1))) void*)g,
                                     (__attribute__((address_space(3))) void*)l, 16, 0, 0);
}

// ---------------------------------------------------------------------------
// Kernel 1: gating — logits = x@wg, softmax, top1/top2 (one wave per token).
// Also emits xb = bf16(x) (+ zero row at ntok).
// ---------------------------------------------------------------------------
__global__ void gating_kernel(const float* __restrict__ x, const float* __restrict__ wg,
                              int* __restrict__ e1o, int* __restrict__ e2o,
                              float* __restrict__ g1o, float* __restrict__ g2o,
                              unsigned short* __restrict__ xb, int ntok) {
    if (blockIdx.x == 0) {
        for (int m = threadIdx.x; m < M_DIM; m += blockDim.x)
            xb[(size_t)ntok * M_DIM + m] = 0;
    }
    int gid  = blockIdx.x * blockDim.x + threadIdx.x;
    int tok  = gid >> 6;
    int lane = threadIdx.x & 63;
    if (tok >= ntok) return;
    const float* xr = x + (size_t)tok * M_DIM;
    unsigned short* xbr = xb + (size_t)tok * M_DIM;
    float acc[E_NUM];
#pragma unroll
    for (int e = 0; e < E_NUM; ++e) acc[e] = 0.f;
    for (int m = lane; m < M_DIM; m += 64) {
        float xv = xr[m];
        xbr[m] = f2bf(xv);
        const float* wr = wg + (size_t)m * E_NUM;
#pragma unroll
        for (int e = 0; e < E_NUM; ++e) acc[e] += xv * wr[e];
    }
#pragma unroll
    for (int off = 32; off >= 1; off >>= 1) {
#pragma unroll
        for (int e = 0; e < E_NUM; ++e) acc[e] += __shfl_xor(acc[e], off, 64);
    }
    if (lane == 0) {
        float mx = acc[0];
#pragma unroll
        for (int e = 1; e < E_NUM; ++e) mx = fmaxf(mx, acc[e]);
        float p[E_NUM]; float s = 0.f;
#pragma unroll
        for (int e = 0; e < E_NUM; ++e) { p[e] = expf(acc[e] - mx); s += p[e]; }
        float inv = 1.f / s;
        int b1 = 0; float v1 = -1.f;
#pragma unroll
        for (int e = 0; e < E_NUM; ++e) { if (p[e] > v1) { v1 = p[e]; b1 = e; } }
        int b2 = 0; float v2 = -1.f;
#pragma unroll
        for (int e = 0; e < E_NUM; ++e) { if (e != b1 && p[e] > v2) { v2 = p[e]; b2 = e; } }
        e1o[tok] = b1; e2o[tok] = b2;
        g1o[tok] = v1 * inv; g2o[tok] = v2 * inv;
    }
}

// ---------------------------------------------------------------------------
// Kernel 2: assignment — capacity positions via ballot prefix scan.
// ---------------------------------------------------------------------------
__global__ void assign_kernel(const int* __restrict__ e1a, const int* __restrict__ e2a,
                              const float* __restrict__ g1a, const float* __restrict__ g2a,
                              int* __restrict__ slot1, int* __restrict__ slot2,
                              float* __restrict__ wslot,
                              int* __restrict__ tfs, int G) {
    int g    = blockIdx.x;
    int tid  = threadIdx.x;
    int w    = tid >> 6;
    int lane = tid & 63;
    __shared__ int cnt1s[E_NUM];

    for (int i = tid; i < E_NUM * CAP; i += 1024) tfs[(size_t)g * E_NUM * CAP + i] = -1;
    __syncthreads();

    {
        int vals[S_TOK / 64];
#pragma unroll
        for (int it = 0; it < S_TOK / 64; ++it) vals[it] = e1a[g * S_TOK + it * 64 + lane];
        int cnt = 0;
#pragma unroll
        for (int it = 0; it < S_TOK / 64; ++it) {
            int base = it * 64;
            int t = g * S_TOK + base + lane;
            bool pred = (vals[it] == w);
            unsigned long long bal = __ballot(pred);
            int prefix = __popcll(bal & ((1ull << lane) - 1ull));
            if (pred) {
                int pos = cnt + prefix;
                if (pos < CAP) {
                    slot1[t] = w * CAP + pos;
                    tfs[((size_t)g * E_NUM + w) * CAP + pos] = base + lane;
                } else {
                    slot1[t] = -1;
                }
            }
            cnt += __popcll(bal);
        }
        if (lane == 0) cnt1s[w] = cnt < CAP ? cnt : CAP;
    }
    __syncthreads();
    {
        int vals[S_TOK / 64];
#pragma unroll
        for (int it = 0; it < S_TOK / 64; ++it) vals[it] = e2a[g * S_TOK + it * 64 + lane];
        int cnt = cnt1s[w];
#pragma unroll
        for (int it = 0; it < S_TOK / 64; ++it) {
            int base = it * 64;
            int t = g * S_TOK + base + lane;
            bool pred = (vals[it] == w);
            unsigned long long bal = __ballot(pred);
            int prefix = __popcll(bal & ((1ull << lane) - 1ull));
            if (pred) {
                int pos = cnt + prefix;
                if (pos < CAP) {
                    slot2[t] = w * CAP + pos;
                    tfs[((size_t)g * E_NUM + w) * CAP + pos] = base + lane;
                } else {
                    slot2[t] = -1;
                }
            }
            cnt += __popcll(bal);
        }
    }
    __syncthreads();
    for (int t = tid; t < S_TOK; t += 1024) {
        int gt = g * S_TOK + t;
        int s1 = slot1[gt], s2 = slot2[gt];
        float a = s1 >= 0 ? g1a[gt] : 0.f;
        float b = s2 >= 0 ? g2a[gt] : 0.f;
        float denom = a + b;
        if (!(denom > 0.f)) denom = 1.f;
        if (s1 >= 0) wslot[(size_t)g * E_NUM * CAP + s1] = a / denom;
        if (s2 >= 0) wslot[(size_t)g * E_NUM * CAP + s2] = b / denom;
    }
}

// ---------------------------------------------------------------------------
// Kernel 3: transpose+convert: src [E][R][C] fp32 -> dst [E][C][R] bf16.
// 64x64 tile, 256 threads; ushort2 stores (full-rate).
// ---------------------------------------------------------------------------
__global__ __launch_bounds__(256) void transpose_conv_kernel(const float* __restrict__ src,
                                                             unsigned short* __restrict__ dst,
                                                             int R, int C) {
    __shared__ float T[64][65];
    int e  = blockIdx.z;
    int c0 = blockIdx.x * 64;
    int r0 = blockIdx.y * 64;
    int tid = threadIdx.x;
    int lx = tid & 63, ly = tid >> 6;
    const float* S = src + (size_t)e * R * C;
#pragma unroll
    for (int i = 0; i < 16; ++i) {
        int r = i * 4 + ly;
        T[r][lx] = S[(size_t)(r0 + r) * C + c0 + lx];
    }
    __syncthreads();
    unsigned short* D = dst + (size_t)e * C * R;
    int r2 = (tid & 31) * 2;
    int cy = tid >> 5;            // 0..7
#pragma unroll
    for (int i = 0; i < 8; ++i) {
        int c = i * 8 + cy;
        ushort2 v;
        v.x = f2bf(T[r2][c]);
        v.y = f2bf(T[r2 + 1][c]);
        *(ushort2*)&D[(size_t)(c0 + c) * R + r0 + r2] = v;
    }
}

// ---------------------------------------------------------------------------
// Unified MFMA GEMM core: 128x128 tile, 256 thr, K-chunk 768 as 12 iters of
// 64 (two BK=32 LDS buffers per barrier). XCD-swizzled grid of 1536 blocks:
//   xcd = bx&7, slot = bx>>3, tile = (slot>>2)*8 + xcd (384), j = slot&3
//   c0 = (j>>1)*128, g = j&1  -> 4 B-tile sharers consecutive on one XCD.
// ---------------------------------------------------------------------------

// gemm1: h[z][CAP][H] = relu(gather(xb) @ wiT[e]^T)
__global__ __launch_bounds__(256) void gemm1_kernel(
        const unsigned short* __restrict__ A,    // xb [ntok+1][M]
        const unsigned short* __restrict__ B,    // wiT [E][H][M]
        const int* __restrict__ tfs,
        unsigned short* __restrict__ Hout, int G, int ntok) {
    __shared__ unsigned short As0[128 * 32], As1[128 * 32];
    __shared__ unsigned short Bs0[128 * 32], Bs1[128 * 32];
    __shared__ int rowtok[128];

    int bx   = blockIdx.x;
    int xcd  = bx & 7;
    int slot = bx >> 3;
    int t    = (slot >> 2) * 8 + xcd;     // 0..383 : e*24 + n_tile
    int j    = slot & 3;
    int e    = t / 24;
    int n0   = (t % 24) * 128;
    int c0   = (j >> 1) * 128;
    int g    = j & 1;
    int z    = e * G + g;
    int tid  = threadIdx.x;

    if (tid < 128) rowtok[tid] = tfs[((size_t)g * E_NUM + e) * CAP + c0 + tid];
    __syncthreads();

    int w = tid >> 6, l = tid & 63;
    int rA  = 16 * w + (l >> 2);          // row within 64-slab
    int seg = l & 3;

    const unsigned short* aRow[2];
    const unsigned short* bRow[2];
#pragma unroll
    for (int p = 0; p < 2; ++p) {
        int tok = rowtok[p * 64 + rA];
        size_t grow = (tok < 0) ? (size_t)ntok : (size_t)(g * S_TOK + tok);
        aRow[p] = A + grow * M_DIM + seg * 8;
        bRow[p] = B + (size_t)e * H_DIM * M_DIM + ((size_t)n0 + p * 64 + rA) * M_DIM + seg * 8;
    }
    unsigned aoff = w * 512 + 0;          // ushort offset within a 64-slab region

    int lane = tid & 63;
    int r = lane & 15, q = lane >> 4;
    int wm = w & 1, wn = w >> 1;

    f32x4 acc[4][4];
#pragma unroll
    for (int i = 0; i < 4; ++i)
#pragma unroll
        for (int jj = 0; jj < 4; ++jj) acc[i][jj] = (f32x4)(0.f);

    for (int k0 = 0; k0 < M_DIM; k0 += 64) {
#pragma unroll
        for (int p = 0; p < 2; ++p) {
            async16(aRow[p] + k0,      As0 + p * 2048 + aoff);
            async16(aRow[p] + k0 + 32, As1 + p * 2048 + aoff);
            async16(bRow[p] + k0,      Bs0 + p * 2048 + aoff);
            async16(bRow[p] + k0 + 32, Bs1 + p * 2048 + aoff);
        }
        __syncthreads();
#pragma unroll
        for (int kk = 0; kk < 2; ++kk) {
            const unsigned short* Asb = kk ? As1 : As0;
            const unsigned short* Bsb = kk ? Bs1 : Bs0;
            s16x8 af[4], bfr[4];
#pragma unroll
            for (int i = 0; i < 4; ++i)
                af[i] = *(const s16x8*)&Asb[(wm * 64 + i * 16 + r) * 32 + q * 8];
#pragma unroll
            for (int jj = 0; jj < 4; ++jj)
                bfr[jj] = *(const s16x8*)&Bsb[(wn * 64 + jj * 16 + r) * 32 + q * 8];
#pragma unroll
            for (int i = 0; i < 4; ++i)
#pragma unroll
                for (int jj = 0; jj < 4; ++jj)
                    acc[i][jj] = __builtin_amdgcn_mfma_f32_16x16x32_bf16(af[i], bfr[jj], acc[i][jj], 0, 0, 0);
        }
        __syncthreads();
    }

#pragma unroll
    for (int i = 0; i < 4; ++i) {
#pragma unroll
        for (int v = 0; v < 4; ++v) {
            int m_loc = wm * 64 + i * 16 + q * 4 + v;
            unsigned short* row = Hout + ((size_t)z * CAP + c0 + m_loc) * H_DIM + n0;
#pragma unroll
            for (int jj = 0; jj < 4; ++jj) {
                int n_loc = wn * 64 + jj * 16 + r;
                row[n_loc] = f2bf(fmaxf(acc[i][jj][v], 0.f));
            }
        }
    }
}

// gemm2: out[token] += wslot * (h @ woT[e]^T), split-K x4
__global__ __launch_bounds__(256) void gemm2_kernel(
        const unsigned short* __restrict__ A,   // h [32][CAP][H]
        const unsigned short* __restrict__ B,   // woT [E][M][H]
        const int* __restrict__ tfs,
        const float* __restrict__ wslot,
        float* __restrict__ out, int G) {
    __shared__ unsigned short As0[128 * 32], As1[128 * 32];
    __shared__ unsigned short Bs0[128 * 32], Bs1[128 * 32];
    __shared__ int   rowtok[128];
    __shared__ float rowwt[128];

    int bx   = blockIdx.x;
    int xcd  = bx & 7;
    int slot = bx >> 3;
    int t    = (slot >> 2) * 8 + xcd;     // 0..383 : e*24 + kc*6 + n_tile
    int j    = slot & 3;
    int e    = t / 24;
    int rem  = t % 24;
    int kc   = rem / 6;
    int n0   = (rem % 6) * 128;
    int c0   = (j >> 1) * 128;
    int g    = j & 1;
    int z    = e * G + g;
    int tid  = threadIdx.x;

    if (tid < 128) {
        size_t sidx = ((size_t)g * E_NUM + e) * CAP + c0 + tid;
        rowtok[tid] = tfs[sidx];
        rowwt[tid]  = wslot[sidx];
    }
    // no barrier needed: rowtok/rowwt consumed only after k-loop barriers

    int w = tid >> 6, l = tid & 63;
    int rA  = 16 * w + (l >> 2);
    int seg = l & 3;
    const int KC = H_DIM / 4;             // 768
    int kb = kc * KC;

    const unsigned short* aRow[2];
    const unsigned short* bRow[2];
#pragma unroll
    for (int p = 0; p < 2; ++p) {
        aRow[p] = A + ((size_t)z * CAP + c0 + p * 64 + rA) * H_DIM + kb + seg * 8;
        bRow[p] = B + (size_t)e * M_DIM * H_DIM + ((size_t)n0 + p * 64 + rA) * H_DIM + kb + seg * 8;
    }
    unsigned aoff = w * 512;

    int lane = tid & 63;
    int r = lane & 15, q = lane >> 4;
    int wm = w & 1, wn = w >> 1;

    f32x4 acc[4][4];
#pragma unroll
    for (int i = 0; i < 4; ++i)
#pragma unroll
        for (int jj = 0; jj < 4; ++jj) acc[i][jj] = (f32x4)(0.f);

    for (int k0 = 0; k0 < KC; k0 += 64) {
#pragma unroll
        for (int p = 0; p < 2; ++p) {
            async16(aRow[p] + k0,      As0 + p * 2048 + aoff);
            async16(aRow[p] + k0 + 32, As1 + p * 2048 + aoff);
            async16(bRow[p] + k0,      Bs0 + p * 2048 + aoff);
            async16(bRow[p] + k0 + 32, Bs1 + p * 2048 + aoff);
        }
        __syncthreads();
#pragma unroll
        for (int kk = 0; kk < 2; ++kk) {
            const unsigned short* Asb = kk ? As1 : As0;
            const unsigned short* Bsb = kk ? Bs1 : Bs0;
            s16x8 af[4], bfr[4];
#pragma unroll
            for (int i = 0; i < 4; ++i)
                af[i] = *(const s16x8*)&Asb[(wm * 64 + i * 16 + r) * 32 + q * 8];
#pragma unroll
            for (int jj = 0; jj < 4; ++jj)
                bfr[jj] = *(const s16x8*)&Bsb[(wn * 64 + jj * 16 + r) * 32 + q * 8];
#pragma unroll
            for (int i = 0; i < 4; ++i)
#pragma unroll
                for (int jj = 0; jj < 4; ++jj)
                    acc[i][jj] = __builtin_amdgcn_mfma_f32_16x16x32_bf16(af[i], bfr[jj], acc[i][jj], 0, 0, 0);
        }
        __syncthreads();
    }

#pragma unroll
    for (int i = 0; i < 4; ++i) {
#pragma unroll
        for (int v = 0; v < 4; ++v) {
            int m_loc = wm * 64 + i * 16 + q * 4 + v;
            int tok = rowtok[m_loc];
            if (tok < 0) continue;
            float wgt = rowwt[m_loc];
            float* orow = out + ((size_t)(g * S_TOK + tok)) * M_DIM + n0;
#pragma unroll
            for (int jj = 0; jj < 4; ++jj) {
                int n_loc = wn * 64 + jj * 16 + r;
                atomicAdd(&orow[n_loc], wgt * acc[i][jj][v]);
            }
        }
    }
}

// ---------------------------------------------------------------------------
__global__ void zero_kernel(float4* __restrict__ p, int n4) {
    int i = blockIdx.x * blockDim.x + threadIdx.x;
    if (i < n4) p[i] = make_float4(0.f, 0.f, 0.f, 0.f);
}

// ---------------------------------------------------------------------------
extern "C" void kernel_launch(void* const* d_in, const int* in_sizes, int n_in,
                              void* d_out, int out_size, void* d_ws, size_t ws_size,
                              hipStream_t stream) {
    const float* x  = (const float*)d_in[0];
    const float* wg = (const float*)d_in[1];
    const float* wi = (const float*)d_in[2];
    const float* wo = (const float*)d_in[3];
    float* out = (float*)d_out;

    int ntok = in_sizes[0] / M_DIM;   // 4096
    int G = ntok / S_TOK;             // 2

    char* wsp = (char*)d_ws;
    auto carve = [&](size_t bytes) {
        void* p = (void*)wsp;
        wsp += (bytes + 255) & ~(size_t)255;
        return p;
    };
    int*   e1    = (int*)carve((size_t)ntok * 4);
    int*   e2    = (int*)carve((size_t)ntok * 4);
    float* g1    = (float*)carve((size_t)ntok * 4);
    float* g2    = (float*)carve((size_t)ntok * 4);
    int*   slot1 = (int*)carve((size_t)ntok * 4);
    int*   slot2 = (int*)carve((size_t)ntok * 4);
    float* wslot = (float*)carve((size_t)G * E_NUM * CAP * 4);
    int*   tfs   = (int*)carve((size_t)G * E_NUM * CAP * 4);
    unsigned short* xb  = (unsigned short*)carve((size_t)(ntok + 1) * M_DIM * 2);
    unsigned short* wiT = (unsigned short*)carve((size_t)E_NUM * H_DIM * M_DIM * 2);
    unsigned short* woT = (unsigned short*)carve((size_t)E_NUM * M_DIM * H_DIM * 2);
    unsigned short* h   = (unsigned short*)carve((size_t)E_NUM * G * CAP * H_DIM * 2);

    gating_kernel<<<(ntok * 64 + 255) / 256, 256, 0, stream>>>(x, wg, e1, e2, g1, g2, xb, ntok);
    assign_kernel<<<G, 1024, 0, stream>>>(e1, e2, g1, g2, slot1, slot2, wslot, tfs, G);

    // wi [E][M][H] -> wiT [E][H][M]
    transpose_conv_kernel<<<dim3(H_DIM / 64, M_DIM / 64, E_NUM), 256, 0, stream>>>(wi, wiT, M_DIM, H_DIM);
    // wo [E][H][M] -> woT [E][M][H]
    transpose_conv_kernel<<<dim3(M_DIM / 64, H_DIM / 64, E_NUM), 256, 0, stream>>>(wo, woT, H_DIM, M_DIM);

    gemm1_kernel<<<1536, 256, 0, stream>>>(xb, wiT, tfs, h, G, ntok);

    int n4 = ntok * M_DIM / 4;
    zero_kernel<<<(n4 + 255) / 256, 256, 0, stream>>>((float4*)out, n4);

    gemm2_kernel<<<1536, 256, 0, stream>>>(h, woT, tfs, wslot, out, G);
}